// Round 1
// baseline (416.316 us; speedup 1.0000x reference)
//
#include <hip/hip_runtime.h>
#include <hip/hip_cooperative_groups.h>

namespace cg = cooperative_groups;

#define LEAKY(v) ((v) > 0.0f ? (v) : 0.2f * (v))

struct Params {
    const float* x;  const int* row; const int* col;
    const float* W1; const float* b1; const float* W2; const float* b2;
    const float* k1; const float* kb1; const float* k2; const float* kb2;
    const float* k3; const float* kb3; const float* k4; const float* kb4;
    const float* fw1; const float* fb1; const float* fw2; const float* fb2;
    const float* fw3; const float* fb3;
    float* deg;   // ws+0      (1024)  -- deg,agg1,agg2 contiguous for bulk zeroing
    float* agg1;  // ws+1024   (32000)
    float* agg2;  // ws+33024  (32000)
    float* xw;    // ws+65024  (32000)
    float* c1;    // ws+97024  (46408, 16B aligned)
    float* c2;    // ws+143432 (44640)
    float* c3;    // ws+188072 (10704)
    float* f1;    // ws+198776 (1024, 16B aligned)
    float* f2;    // ws+199800 (1024, 16B aligned)
    float* out;
    int n; int E;
};

// Single cooperative kernel: all 10 former dispatches as phases separated by
// grid.sync(). 256 blocks x 256 threads = 1 wg/CU, trivially co-resident.
// Rationale: total real work is ~10 MFLOP / ~12 MB -> intrinsic floor ~20 us;
// the 136 us baseline was ~11 dispatches x ~12 us serialization overhead.
__global__ __launch_bounds__(256) void fused_all(Params p) {
    cg::grid_group grid = cg::this_grid();
    const int T  = blockIdx.x * 256 + (int)threadIdx.x;
    const int NT = gridDim.x * 256;
    __shared__ __align__(16) float lc4[1680];

    // ---- P0: zero deg + agg1 + agg2 (contiguous: 1024 + 64000 floats) ----
    for (int i = T; i < 1024 + 64000; i += NT) p.deg[i] = 0.0f;
    grid.sync();

    // ---- P1: degree atomics (edges only; self-loop folded as +1 later) and
    //          xw1 = x @ W1 using features 3..5 (0..2 zeroed by forward) ----
    for (int e = T; e < p.E; e += NT) atomicAdd(&p.deg[p.col[e]], 1.0f);
    for (int t = T; t < p.n * 32; t += NT) {
        int j = t & 31, nn = t >> 5;
        p.xw[t] = p.x[nn*6+3] * p.W1[96+j]
                + p.x[nn*6+4] * p.W1[128+j]
                + p.x[nn*6+5] * p.W1[160+j];
    }
    grid.sync();

    // ---- P2: scatter1  agg1[col] += xw[row] * norm (incl. self-loops) ----
    {
        const int total = (p.E + p.n) * 32;
        for (int t = T; t < total; t += NT) {
            int e = t >> 5, j = t & 31;
            int r, c; float nrm;
            if (e < p.E) {
                r = p.row[e]; c = p.col[e];
                nrm = (1.0f / sqrtf(p.deg[r] + 1.0f)) * (1.0f / sqrtf(p.deg[c] + 1.0f));
            } else {
                r = c = e - p.E;
                nrm = 1.0f / (p.deg[r] + 1.0f);
            }
            atomicAdd(&p.agg1[c * 32 + j], p.xw[r * 32 + j] * nrm);
        }
    }
    grid.sync();

    // ---- P3: xw = leaky(agg1 + b1) @ W2 ----
    for (int t = T; t < p.n * 32; t += NT) {
        int j = t & 31, nn = t >> 5;
        const float* a = p.agg1 + nn * 32;
        float s = 0.0f;
#pragma unroll
        for (int f = 0; f < 32; ++f) {
            float v = a[f] + p.b1[f];
            v = LEAKY(v);
            s += v * p.W2[f * 32 + j];
        }
        p.xw[t] = s;
    }
    grid.sync();

    // ---- P4: scatter2 -> agg2 ----
    {
        const int total = (p.E + p.n) * 32;
        for (int t = T; t < total; t += NT) {
            int e = t >> 5, j = t & 31;
            int r, c; float nrm;
            if (e < p.E) {
                r = p.row[e]; c = p.col[e];
                nrm = (1.0f / sqrtf(p.deg[r] + 1.0f)) * (1.0f / sqrtf(p.deg[c] + 1.0f));
            } else {
                r = c = e - p.E;
                nrm = 1.0f / (p.deg[r] + 1.0f);
            }
            atomicAdd(&p.agg2[c * 32 + j], p.xw[r * 32 + j] * nrm);
        }
    }
    grid.sync();

    // ---- P5: conv1 (+b2, leaky on input) + relu + pool -> c1 [3,499,31] ----
    {
        const int Hp = 499, Wo = 31, total = 3 * Hp * Wo;
        for (int t0 = T; t0 < total; t0 += NT) {
            int ow = t0 % Wo; int t = t0 / Wo; int oh = t % Hp; int co = t / Hp;
            const float* ip = p.agg2 + (2 * oh) * 32 + ow;
            float vals[4][2];
#pragma unroll
            for (int r = 0; r < 4; ++r)
#pragma unroll
                for (int cx = 0; cx < 2; ++cx) {
                    float v = ip[r * 32 + cx] + p.b2[ow + cx];
                    vals[r][cx] = LEAKY(v);
                }
            const float* wp = p.k1 + co * 6;
            float a0 = vals[0][0]*wp[0] + vals[0][1]*wp[1] + vals[1][0]*wp[2]
                     + vals[1][1]*wp[3] + vals[2][0]*wp[4] + vals[2][1]*wp[5];
            float a1 = vals[1][0]*wp[0] + vals[1][1]*wp[1] + vals[2][0]*wp[2]
                     + vals[2][1]*wp[3] + vals[3][0]*wp[4] + vals[3][1]*wp[5];
            float m = fmaxf(a0, a1) + p.kb1[co];
            p.c1[t0] = fmaxf(m, 0.0f);
        }
    }
    grid.sync();

    // ---- P6: conv2 -> c2 [6,248,30] ----
    {
        const int CI = 3, Hin = 499, Win = 31, Hp = 248, Wo = 30, total = 6 * Hp * Wo;
        for (int t0 = T; t0 < total; t0 += NT) {
            int ow = t0 % Wo; int t = t0 / Wo; int oh = t % Hp; int co = t / Hp;
            float a0 = 0.0f, a1 = 0.0f;
#pragma unroll
            for (int ci = 0; ci < CI; ++ci) {
                const float* q = p.c1 + (ci * Hin + 2 * oh) * Win + ow;
                const float* wp = p.k2 + (co * CI + ci) * 6;
                float r00 = q[0],     r01 = q[1];
                float r10 = q[Win],   r11 = q[Win+1];
                float r20 = q[2*Win], r21 = q[2*Win+1];
                float r30 = q[3*Win], r31 = q[3*Win+1];
                a0 += r00*wp[0] + r01*wp[1] + r10*wp[2] + r11*wp[3] + r20*wp[4] + r21*wp[5];
                a1 += r10*wp[0] + r11*wp[1] + r20*wp[2] + r21*wp[3] + r30*wp[4] + r31*wp[5];
            }
            float m = fmaxf(a0, a1) + p.kb2[co];
            p.c2[t0] = fmaxf(m, 0.0f);
        }
    }
    grid.sync();

    // ---- P7: conv3 -> c3 [3,123,29] ----
    {
        const int CI = 6, Hin = 248, Win = 30, Hp = 123, Wo = 29, total = 3 * Hp * Wo;
        for (int t0 = T; t0 < total; t0 += NT) {
            int ow = t0 % Wo; int t = t0 / Wo; int oh = t % Hp; int co = t / Hp;
            float a0 = 0.0f, a1 = 0.0f;
#pragma unroll
            for (int ci = 0; ci < CI; ++ci) {
                const float* q = p.c2 + (ci * Hin + 2 * oh) * Win + ow;
                const float* wp = p.k3 + (co * CI + ci) * 6;
                float r00 = q[0],     r01 = q[1];
                float r10 = q[Win],   r11 = q[Win+1];
                float r20 = q[2*Win], r21 = q[2*Win+1];
                float r30 = q[3*Win], r31 = q[3*Win+1];
                a0 += r00*wp[0] + r01*wp[1] + r10*wp[2] + r11*wp[3] + r20*wp[4] + r21*wp[5];
                a1 += r10*wp[0] + r11*wp[1] + r20*wp[2] + r21*wp[3] + r30*wp[4] + r31*wp[5];
            }
            float m = fmaxf(a0, a1) + p.kb3[co];
            p.c3[t0] = fmaxf(m, 0.0f);
        }
    }
    grid.sync();

    // ---- P8: conv4 (redundant per block, tiny) into LDS, then FC1 row
    //          o = blockIdx*4 + wave. Redundancy (~33 MFLOP grid-wide) is
    //          cheaper than one more grid.sync. ----
    {
        const int Hin = 123, Win = 29, Wo = 28;
        float kb = p.kb4[0];
        for (int t0 = (int)threadIdx.x; t0 < 1680; t0 += 256) {
            int ow = t0 % Wo; int oh = t0 / Wo;
            float a0 = 0.0f, a1 = 0.0f;
#pragma unroll
            for (int ci = 0; ci < 3; ++ci) {
                const float* q = p.c3 + (ci * Hin + 2 * oh) * Win + ow;
                const float* wp = p.k4 + ci * 6;
                float r00 = q[0],     r01 = q[1];
                float r10 = q[Win],   r11 = q[Win+1];
                float r20 = q[2*Win], r21 = q[2*Win+1];
                float r30 = q[3*Win], r31 = q[3*Win+1];
                a0 += r00*wp[0] + r01*wp[1] + r10*wp[2] + r11*wp[3] + r20*wp[4] + r21*wp[5];
                a1 += r10*wp[0] + r11*wp[1] + r20*wp[2] + r21*wp[3] + r30*wp[4] + r31*wp[5];
            }
            float m = fmaxf(a0, a1) + kb;
            lc4[t0] = fmaxf(m, 0.0f);
        }
        __syncthreads();
        int wv = (int)threadIdx.x >> 6, lane = (int)threadIdx.x & 63;
        int o = blockIdx.x * 4 + wv;   // 256 blocks * 4 waves = 1024 rows exactly
        const float4* wr = (const float4*)(p.fw1 + (size_t)o * 1680);
        const float4* vv = (const float4*)lc4;
        float s = 0.0f;
        for (int i = lane; i < 420; i += 64) {
            float4 a = vv[i], ww = wr[i];
            s += a.x*ww.x + a.y*ww.y + a.z*ww.z + a.w*ww.w;
        }
#pragma unroll
        for (int off = 32; off > 0; off >>= 1) s += __shfl_down(s, off, 64);
        if (lane == 0) p.f1[o] = s + p.fb1[o];
    }
    grid.sync();

    // ---- P9: FC2 (1024x1024), one wave per row ----
    {
        int wv = (int)threadIdx.x >> 6, lane = (int)threadIdx.x & 63;
        int o = blockIdx.x * 4 + wv;
        const float4* wr = (const float4*)(p.fw2 + (size_t)o * 1024);
        const float4* vv = (const float4*)p.f1;
        float s = 0.0f;
#pragma unroll
        for (int i = 0; i < 4; ++i) {
            float4 a = vv[lane + 64*i], ww = wr[lane + 64*i];
            s += a.x*ww.x + a.y*ww.y + a.z*ww.z + a.w*ww.w;
        }
#pragma unroll
        for (int off = 32; off > 0; off >>= 1) s += __shfl_down(s, off, 64);
        if (lane == 0) p.f2[o] = s + p.fb2[o];
    }
    grid.sync();

    // ---- P10: FC3 (64x1024) -> out; blocks 0..15 only ----
    if (blockIdx.x < 16) {
        int wv = (int)threadIdx.x >> 6, lane = (int)threadIdx.x & 63;
        int o = blockIdx.x * 4 + wv;
        const float4* wr = (const float4*)(p.fw3 + (size_t)o * 1024);
        const float4* vv = (const float4*)p.f2;
        float s = 0.0f;
#pragma unroll
        for (int i = 0; i < 4; ++i) {
            float4 a = vv[lane + 64*i], ww = wr[lane + 64*i];
            s += a.x*ww.x + a.y*ww.y + a.z*ww.z + a.w*ww.w;
        }
#pragma unroll
        for (int off = 32; off > 0; off >>= 1) s += __shfl_down(s, off, 64);
        if (lane == 0) p.out[o] = s + p.fb3[o];
    }
}

extern "C" void kernel_launch(void* const* d_in, const int* in_sizes, int n_in,
                              void* d_out, int out_size, void* d_ws, size_t ws_size,
                              hipStream_t stream) {
    Params hp;
    hp.x   = (const float*)d_in[0];
    const int* ei = (const int*)d_in[1];
    hp.W1  = (const float*)d_in[2];
    hp.b1  = (const float*)d_in[3];
    hp.W2  = (const float*)d_in[4];
    hp.b2  = (const float*)d_in[5];
    hp.k1  = (const float*)d_in[6];
    hp.kb1 = (const float*)d_in[7];
    hp.k2  = (const float*)d_in[8];
    hp.kb2 = (const float*)d_in[9];
    hp.k3  = (const float*)d_in[10];
    hp.kb3 = (const float*)d_in[11];
    hp.k4  = (const float*)d_in[12];
    hp.kb4 = (const float*)d_in[13];
    hp.fw1 = (const float*)d_in[14];
    hp.fb1 = (const float*)d_in[15];
    hp.fw2 = (const float*)d_in[16];
    hp.fb2 = (const float*)d_in[17];
    hp.fw3 = (const float*)d_in[18];
    hp.fb3 = (const float*)d_in[19];

    hp.n = in_sizes[0] / 6;        // 1000
    hp.E = in_sizes[1] / 2;        // 8000
    hp.row = ei;
    hp.col = ei + hp.E;

    float* ws = (float*)d_ws;
    hp.deg  = ws;                  // 1024
    hp.agg1 = ws + 1024;           // 32000
    hp.agg2 = hp.agg1 + 32000;     // 32000
    hp.xw   = hp.agg2 + 32000;     // 32000
    hp.c1   = hp.xw + 32000;       // 46408 (padded, 16B aligned start)
    hp.c2   = hp.c1 + 46408;       // 44640
    hp.c3   = hp.c2 + 44640;       // 10704 (padded)
    hp.f1   = hp.c3 + 10704;       // 1024 (16B aligned)
    hp.f2   = hp.f1 + 1024;        // 1024 (16B aligned)
    hp.out  = (float*)d_out;

    void* args[] = { (void*)&hp };
    hipLaunchCooperativeKernel((void*)fused_all, dim3(256), dim3(256), args, 0, stream);
}

// Round 3
// 204.457 us; speedup vs baseline: 2.0362x; 2.0362x over previous
//
#include <hip/hip_runtime.h>

#define LEAKY(v) ((v) > 0.0f ? (v) : 0.2f * (v))

// ---- kA: zero agg1+agg2; deg by replicated scan (no atomics, no memset);
//          M = fw3 @ fw2 (64x1024, data-independent; folds FC2+FC3 later) ----
__global__ __launch_bounds__(256) void kA_prep(
        const int* __restrict__ col, const float* __restrict__ fw2,
        const float* __restrict__ fw3, float* __restrict__ deg,
        float* __restrict__ aggs /*agg1,agg2 contiguous*/,
        float* __restrict__ M, int n, int E) {
    int T = blockIdx.x * 256 + (int)threadIdx.x;
    // zero agg1+agg2 (2*n*32 = 64000 <= 65536 threads: one store each)
    if (T < 2 * n * 32) aggs[T] = 0.0f;
    // deg scan: one wave per node (n=1000 <= 1024 waves)
    int wave = T >> 6, lane = T & 63;
    if (wave < n) {
        int cnt = 0;
        for (int e = lane; e < E; e += 64) cnt += (col[e] == wave) ? 1 : 0;
#pragma unroll
        for (int off = 32; off > 0; off >>= 1) cnt += __shfl_down(cnt, off, 64);
        if (lane == 0) deg[wave] = (float)cnt;
    }
    // M[k][i] = sum_j fw3[k][j]*fw2[j][i]; blocks 0..63: 16 i-tiles x 4 k-tiles
    if (blockIdx.x < 64) {
        int it = (blockIdx.x & 15) * 64;      // i-tile base (16 tiles of 64)
        int kt = (blockIdx.x >> 4) * 16;      // k-tile base (4 tiles of 16)
        int w  = (int)threadIdx.x >> 6;       // wave 0..3 -> 4 k each
        int i  = it + ((int)threadIdx.x & 63);
        int k0 = kt + w * 4;
        float a0 = 0.f, a1 = 0.f, a2 = 0.f, a3 = 0.f;
        const float* f30 = fw3 + (size_t)k0 * 1024;
        for (int j = 0; j < 1024; ++j) {
            float wv = fw2[j * 1024 + i];
            a0 += f30[j]        * wv;
            a1 += f30[1024 + j] * wv;
            a2 += f30[2048 + j] * wv;
            a3 += f30[3072 + j] * wv;
        }
        M[(size_t)(k0 + 0) * 1024 + i] = a0;
        M[(size_t)(k0 + 1) * 1024 + i] = a1;
        M[(size_t)(k0 + 2) * 1024 + i] = a2;
        M[(size_t)(k0 + 3) * 1024 + i] = a3;
    }
}

// ---- kB: scatter1 with x@W1 inlined (features 3..5 only) ----
__global__ void kB_scatter1(const float* __restrict__ x, const float* __restrict__ W1,
        const float* __restrict__ deg, const int* __restrict__ row,
        const int* __restrict__ col, float* __restrict__ agg1, int E, int n) {
    int tid = blockIdx.x * blockDim.x + threadIdx.x;
    int total = (E + n) * 32;
    if (tid >= total) return;
    int e = tid >> 5, j = tid & 31;
    int r, c; float nrm;
    if (e < E) {
        r = row[e]; c = col[e];
        nrm = (1.0f / sqrtf(deg[r] + 1.0f)) * (1.0f / sqrtf(deg[c] + 1.0f));
    } else {
        r = c = e - E;
        nrm = 1.0f / (deg[r] + 1.0f);
    }
    float val = x[r*6+3] * W1[96+j] + x[r*6+4] * W1[128+j] + x[r*6+5] * W1[160+j];
    atomicAdd(&agg1[c * 32 + j], val * nrm);
}

// ---- kC: scatter2 with h2 = leaky(agg1+b1)@W2 recomputed per edge (~9x
//          redundant, ~9 MFLOP total -> free; kills the separate GEMM dispatch) ----
__global__ void kC_scatter2(const float* __restrict__ agg1, const float* __restrict__ b1,
        const float* __restrict__ W2, const float* __restrict__ deg,
        const int* __restrict__ row, const int* __restrict__ col,
        float* __restrict__ agg2, int E, int n) {
    int tid = blockIdx.x * blockDim.x + threadIdx.x;
    int total = (E + n) * 32;
    if (tid >= total) return;
    int e = tid >> 5, j = tid & 31;
    int r, c; float nrm;
    if (e < E) {
        r = row[e]; c = col[e];
        nrm = (1.0f / sqrtf(deg[r] + 1.0f)) * (1.0f / sqrtf(deg[c] + 1.0f));
    } else {
        r = c = e - E;
        nrm = 1.0f / (deg[r] + 1.0f);
    }
    const float* a = agg1 + r * 32;
    float s = 0.0f;
#pragma unroll
    for (int f = 0; f < 32; ++f) {
        float v = a[f] + b1[f];
        v = LEAKY(v);
        s += v * W2[f * 32 + j];
    }
    atomicAdd(&agg2[c * 32 + j], s * nrm);
}

// ---- kD: conv1+conv2+conv3 deep-fused. One thread per c3 output recomputes
//          its receptive field from agg2 (rows 8oh..8oh+21, cols ow..ow+3).
//          c1/c2 never materialized; kills 2 dispatch boundaries. ----
__global__ __launch_bounds__(256) void kD_c3(const float* __restrict__ agg2,
        const float* __restrict__ b2,
        const float* __restrict__ k1w, const float* __restrict__ kb1,
        const float* __restrict__ k2w, const float* __restrict__ kb2,
        const float* __restrict__ k3w, const float* __restrict__ kb3,
        float* __restrict__ c3) {
    const int total = 3 * 123 * 29;
    int t0 = blockIdx.x * 256 + (int)threadIdx.x;
    if (t0 >= total) return;
    int ow = t0 % 29; int tt = t0 / 29; int oh = tt % 123; int co = tt / 123;

    // c1 values: ci 0..2, c1 rows 4oh..4oh+9 (local hh), cols ow..ow+2 (local cc)
    float c1v[3][10][3];
#pragma unroll
    for (int ci = 0; ci < 3; ++ci) {
        const float* kw = k1w + ci * 6;
        float kb = kb1[ci];
#pragma unroll
        for (int hh = 0; hh < 10; ++hh) {
            int r0 = (4 * oh + hh) * 2;          // agg2 base row (max 997)
#pragma unroll
            for (int cc = 0; cc < 3; ++cc) {
                int c0 = ow + cc;                // agg2 base col (max 30)
                float v[4][2];
#pragma unroll
                for (int rr = 0; rr < 4; ++rr)
#pragma unroll
                    for (int dc = 0; dc < 2; ++dc) {
                        float u = agg2[(r0 + rr) * 32 + c0 + dc] + b2[c0 + dc];
                        v[rr][dc] = LEAKY(u);
                    }
                float a0 = v[0][0]*kw[0] + v[0][1]*kw[1] + v[1][0]*kw[2]
                         + v[1][1]*kw[3] + v[2][0]*kw[4] + v[2][1]*kw[5];
                float a1 = v[1][0]*kw[0] + v[1][1]*kw[1] + v[2][0]*kw[2]
                         + v[2][1]*kw[3] + v[3][0]*kw[4] + v[3][1]*kw[5];
                c1v[ci][hh][cc] = fmaxf(fmaxf(a0, a1) + kb, 0.0f);
            }
        }
    }

    // c2 window (rows 2oh..2oh+3 local r, cols ow..ow+1 local c) per co2,
    // consumed immediately by conv3 accumulation
    float A0 = 0.0f, A1 = 0.0f;
#pragma unroll
    for (int co2 = 0; co2 < 6; ++co2) {
        float c2v[4][2];
        float kb = kb2[co2];
#pragma unroll
        for (int r = 0; r < 4; ++r) {
#pragma unroll
            for (int c = 0; c < 2; ++c) {
                float p0 = 0.0f, p1 = 0.0f;
#pragma unroll
                for (int ci = 0; ci < 3; ++ci) {
                    const float* kw = k2w + (co2 * 3 + ci) * 6;
                    p0 += c1v[ci][2*r  ][c]*kw[0] + c1v[ci][2*r  ][c+1]*kw[1]
                        + c1v[ci][2*r+1][c]*kw[2] + c1v[ci][2*r+1][c+1]*kw[3]
                        + c1v[ci][2*r+2][c]*kw[4] + c1v[ci][2*r+2][c+1]*kw[5];
                    p1 += c1v[ci][2*r+1][c]*kw[0] + c1v[ci][2*r+1][c+1]*kw[1]
                        + c1v[ci][2*r+2][c]*kw[2] + c1v[ci][2*r+2][c+1]*kw[3]
                        + c1v[ci][2*r+3][c]*kw[4] + c1v[ci][2*r+3][c+1]*kw[5];
                }
                c2v[r][c] = fmaxf(fmaxf(p0, p1) + kb, 0.0f);
            }
        }
        const float* kw3 = k3w + (co * 6 + co2) * 6;
        A0 += c2v[0][0]*kw3[0] + c2v[0][1]*kw3[1] + c2v[1][0]*kw3[2]
            + c2v[1][1]*kw3[3] + c2v[2][0]*kw3[4] + c2v[2][1]*kw3[5];
        A1 += c2v[1][0]*kw3[0] + c2v[1][1]*kw3[1] + c2v[2][0]*kw3[2]
            + c2v[2][1]*kw3[3] + c2v[3][0]*kw3[4] + c2v[3][1]*kw3[5];
    }
    c3[t0] = fmaxf(fmaxf(A0, A1) + kb3[co], 0.0f);
}

// ---- kE: conv4 (redundant per block) into LDS, then FC1 rows (VERBATIM
//          from the verified 136us kernel) ----
__global__ __launch_bounds__(256) void kE_conv4_fc1(
        const float* __restrict__ c3, const float* __restrict__ k4,
        const float* __restrict__ kb4, const float* __restrict__ fw1,
        const float* __restrict__ fb1, float* __restrict__ f1) {
    __shared__ __align__(16) float lc4[1680];
    const int Hin = 123, Win = 29, Wo = 28;
    float kb = kb4[0];
    for (int t0 = (int)threadIdx.x; t0 < 1680; t0 += 256) {
        int ow = t0 % Wo; int oh = t0 / Wo;
        float a0 = 0.0f, a1 = 0.0f;
#pragma unroll
        for (int ci = 0; ci < 3; ++ci) {
            const float* q = c3 + (ci * Hin + 2 * oh) * Win + ow;
            const float* wp = k4 + ci * 6;
            float r00 = q[0],     r01 = q[1];
            float r10 = q[Win],   r11 = q[Win+1];
            float r20 = q[2*Win], r21 = q[2*Win+1];
            float r30 = q[3*Win], r31 = q[3*Win+1];
            a0 += r00*wp[0] + r01*wp[1] + r10*wp[2] + r11*wp[3] + r20*wp[4] + r21*wp[5];
            a1 += r10*wp[0] + r11*wp[1] + r20*wp[2] + r21*wp[3] + r30*wp[4] + r31*wp[5];
        }
        float m = fmaxf(a0, a1) + kb;
        lc4[t0] = fmaxf(m, 0.0f);
    }
    __syncthreads();
    int wv = (int)threadIdx.x >> 6, lane = (int)threadIdx.x & 63;
    int o = blockIdx.x * 4 + wv;
    const float4* wr = (const float4*)(fw1 + (size_t)o * 1680);
    const float4* vv = (const float4*)lc4;
    float s = 0.0f;
    for (int i = lane; i < 420; i += 64) {
        float4 a = vv[i], ww = wr[i];
        s += a.x*ww.x + a.y*ww.y + a.z*ww.z + a.w*ww.w;
    }
#pragma unroll
    for (int off = 32; off > 0; off >>= 1) s += __shfl_down(s, off, 64);
    if (lane == 0) f1[o] = s + fb1[o];
}

// ---- kF: out = M @ f1 + (fw3 @ fb2 + fb3). One wave per output row.
//          Folds FC2+FC3 into one tiny dispatch via precomputed M. ----
__global__ __launch_bounds__(256) void kF_head(const float* __restrict__ f1,
        const float* __restrict__ M, const float* __restrict__ fw3,
        const float* __restrict__ fb2, const float* __restrict__ fb3,
        float* __restrict__ out) {
    int wv = (int)threadIdx.x >> 6, lane = (int)threadIdx.x & 63;
    int k = blockIdx.x * 4 + wv;   // 16 blocks x 4 waves = 64 rows
    const float4* Mr = (const float4*)(M + (size_t)k * 1024);
    const float4* vv = (const float4*)f1;
    const float4* f3 = (const float4*)(fw3 + (size_t)k * 1024);
    const float4* bb = (const float4*)fb2;
    float s = 0.0f;
#pragma unroll
    for (int i2 = 0; i2 < 4; ++i2) {
        float4 a = vv[lane + 64*i2], ww = Mr[lane + 64*i2];
        s += a.x*ww.x + a.y*ww.y + a.z*ww.z + a.w*ww.w;
        float4 c = bb[lane + 64*i2], w3 = f3[lane + 64*i2];
        s += c.x*w3.x + c.y*w3.y + c.z*w3.z + c.w*w3.w;
    }
#pragma unroll
    for (int off = 32; off > 0; off >>= 1) s += __shfl_down(s, off, 64);
    if (lane == 0) out[k] = s + fb3[k];
}

extern "C" void kernel_launch(void* const* d_in, const int* in_sizes, int n_in,
                              void* d_out, int out_size, void* d_ws, size_t ws_size,
                              hipStream_t stream) {
    const float* x   = (const float*)d_in[0];
    const int*   ei  = (const int*)d_in[1];
    const float* W1  = (const float*)d_in[2];
    const float* b1  = (const float*)d_in[3];
    const float* W2  = (const float*)d_in[4];
    const float* b2  = (const float*)d_in[5];
    const float* k1  = (const float*)d_in[6];
    const float* kb1 = (const float*)d_in[7];
    const float* k2  = (const float*)d_in[8];
    const float* kb2 = (const float*)d_in[9];
    const float* k3  = (const float*)d_in[10];
    const float* kb3 = (const float*)d_in[11];
    const float* k4  = (const float*)d_in[12];
    const float* kb4 = (const float*)d_in[13];
    const float* fw1 = (const float*)d_in[14];
    const float* fb1 = (const float*)d_in[15];
    const float* fw2 = (const float*)d_in[16];
    const float* fb2 = (const float*)d_in[17];
    const float* fw3 = (const float*)d_in[18];
    const float* fb3 = (const float*)d_in[19];

    int n = in_sizes[0] / 6;       // 1000
    int E = in_sizes[1] / 2;       // 8000
    const int* row = ei;
    const int* col = ei + E;

    float* ws   = (float*)d_ws;
    float* deg  = ws;              // 1024
    float* agg1 = ws + 1024;       // 32000 (agg1+agg2 contiguous for kA zeroing)
    float* agg2 = agg1 + 32000;    // 32000
    float* M    = agg2 + 32000;    // 65536 (16B aligned)
    float* c3   = M + 65536;       // 10704 (padded)
    float* f1   = c3 + 10704;      // 1024 (16B aligned)

    const int B = 256;
    int st = (E + n) * 32;

    kA_prep<<<256, B, 0, stream>>>(col, fw2, fw3, deg, agg1, M, n, E);
    kB_scatter1<<<(st + B - 1) / B, B, 0, stream>>>(x, W1, deg, row, col, agg1, E, n);
    kC_scatter2<<<(st + B - 1) / B, B, 0, stream>>>(agg1, b1, W2, deg, row, col, agg2, E, n);
    kD_c3<<<(3 * 123 * 29 + B - 1) / B, B, 0, stream>>>(agg2, b2, k1, kb1, k2, kb2, k3, kb3, c3);
    kE_conv4_fc1<<<256, B, 0, stream>>>(c3, k4, kb4, fw1, fb1, f1);
    kF_head<<<16, B, 0, stream>>>(f1, M, fw3, fb2, fb3, (float*)d_out);
}

// Round 4
// 172.856 us; speedup vs baseline: 2.4085x; 1.1828x over previous
//
#include <hip/hip_runtime.h>

#define LEAKY(v) ((v) > 0.0f ? (v) : 0.2f * (v))

// ---- kA: zero agg1+agg2; deg by replicated scan (no atomics, no memset);
//          Mpart[jc][k][i] = partial fw3@fw2 over j-chunk jc.
//          j-split across ALL 256 blocks (fix for round-3's latency-bound
//          64-block / 1024-serial-load version that cost 90us). ----
__global__ __launch_bounds__(256) void kA_prep(
        const int* __restrict__ col, const float* __restrict__ fw2,
        const float* __restrict__ fw3, float* __restrict__ deg,
        float* __restrict__ aggs /*agg1,agg2 contiguous*/,
        float* __restrict__ Mpart, int n, int E) {
    int T = blockIdx.x * 256 + (int)threadIdx.x;
    // zero agg1+agg2 (2*n*32 = 64000 <= 65536 threads: one store each)
    if (T < 2 * n * 32) aggs[T] = 0.0f;
    // deg scan: one wave per node (n=1000 <= 1024 waves)
    int wave = T >> 6, lane = T & 63;
    if (wave < n) {
        int cnt = 0;
        for (int e = lane; e < E; e += 64) cnt += (col[e] == wave) ? 1 : 0;
#pragma unroll
        for (int off = 32; off > 0; off >>= 1) cnt += __shfl_down(cnt, off, 64);
        if (lane == 0) deg[wave] = (float)cnt;
    }
    // Mpart: block b -> j-chunk jc = b>>4 (64 j), i-tile it = (b&15)*64.
    // wave w handles k in [16w, 16w+16); lane -> i = it + lane.
    {
        int jc = blockIdx.x >> 4;
        int it = (blockIdx.x & 15) * 64;
        int w  = (int)threadIdx.x >> 6;
        int i  = it + ((int)threadIdx.x & 63);
        int j0 = jc * 64;
        float acc[16];
#pragma unroll
        for (int kk = 0; kk < 16; ++kk) acc[kk] = 0.0f;
        const float* f3 = fw3 + (size_t)(w * 16) * 1024 + j0;   // rows 16w..16w+15
        for (int jj = 0; jj < 64; ++jj) {
            float wv = fw2[(size_t)(j0 + jj) * 1024 + i];       // coalesced 256B/wave
#pragma unroll
            for (int kk = 0; kk < 16; ++kk)
                acc[kk] += f3[(size_t)kk * 1024 + jj] * wv;     // wave-uniform (scalar path)
        }
#pragma unroll
        for (int kk = 0; kk < 16; ++kk)
            Mpart[(size_t)(jc * 64 + w * 16 + kk) * 1024 + i] = acc[kk];
    }
}

// ---- kB: scatter1 with x@W1 inlined (features 3..5 only) ----
__global__ void kB_scatter1(const float* __restrict__ x, const float* __restrict__ W1,
        const float* __restrict__ deg, const int* __restrict__ row,
        const int* __restrict__ col, float* __restrict__ agg1, int E, int n) {
    int tid = blockIdx.x * blockDim.x + threadIdx.x;
    int total = (E + n) * 32;
    if (tid >= total) return;
    int e = tid >> 5, j = tid & 31;
    int r, c; float nrm;
    if (e < E) {
        r = row[e]; c = col[e];
        nrm = (1.0f / sqrtf(deg[r] + 1.0f)) * (1.0f / sqrtf(deg[c] + 1.0f));
    } else {
        r = c = e - E;
        nrm = 1.0f / (deg[r] + 1.0f);
    }
    float val = x[r*6+3] * W1[96+j] + x[r*6+4] * W1[128+j] + x[r*6+5] * W1[160+j];
    atomicAdd(&agg1[c * 32 + j], val * nrm);
}

// ---- kC: scatter2 with h2 = leaky(agg1+b1)@W2 recomputed per edge ----
__global__ void kC_scatter2(const float* __restrict__ agg1, const float* __restrict__ b1,
        const float* __restrict__ W2, const float* __restrict__ deg,
        const int* __restrict__ row, const int* __restrict__ col,
        float* __restrict__ agg2, int E, int n) {
    int tid = blockIdx.x * blockDim.x + threadIdx.x;
    int total = (E + n) * 32;
    if (tid >= total) return;
    int e = tid >> 5, j = tid & 31;
    int r, c; float nrm;
    if (e < E) {
        r = row[e]; c = col[e];
        nrm = (1.0f / sqrtf(deg[r] + 1.0f)) * (1.0f / sqrtf(deg[c] + 1.0f));
    } else {
        r = c = e - E;
        nrm = 1.0f / (deg[r] + 1.0f);
    }
    const float* a = agg1 + r * 32;
    float s = 0.0f;
#pragma unroll
    for (int f = 0; f < 32; ++f) {
        float v = a[f] + b1[f];
        v = LEAKY(v);
        s += v * W2[f * 32 + j];
    }
    atomicAdd(&agg2[c * 32 + j], s * nrm);
}

// ---- kD: conv1+conv2+conv3 deep-fused (unchanged, passed round 3) ----
__global__ __launch_bounds__(256) void kD_c3(const float* __restrict__ agg2,
        const float* __restrict__ b2,
        const float* __restrict__ k1w, const float* __restrict__ kb1,
        const float* __restrict__ k2w, const float* __restrict__ kb2,
        const float* __restrict__ k3w, const float* __restrict__ kb3,
        float* __restrict__ c3) {
    const int total = 3 * 123 * 29;
    int t0 = blockIdx.x * 256 + (int)threadIdx.x;
    if (t0 >= total) return;
    int ow = t0 % 29; int tt = t0 / 29; int oh = tt % 123; int co = tt / 123;

    float c1v[3][10][3];
#pragma unroll
    for (int ci = 0; ci < 3; ++ci) {
        const float* kw = k1w + ci * 6;
        float kb = kb1[ci];
#pragma unroll
        for (int hh = 0; hh < 10; ++hh) {
            int r0 = (4 * oh + hh) * 2;
#pragma unroll
            for (int cc = 0; cc < 3; ++cc) {
                int c0 = ow + cc;
                float v[4][2];
#pragma unroll
                for (int rr = 0; rr < 4; ++rr)
#pragma unroll
                    for (int dc = 0; dc < 2; ++dc) {
                        float u = agg2[(r0 + rr) * 32 + c0 + dc] + b2[c0 + dc];
                        v[rr][dc] = LEAKY(u);
                    }
                float a0 = v[0][0]*kw[0] + v[0][1]*kw[1] + v[1][0]*kw[2]
                         + v[1][1]*kw[3] + v[2][0]*kw[4] + v[2][1]*kw[5];
                float a1 = v[1][0]*kw[0] + v[1][1]*kw[1] + v[2][0]*kw[2]
                         + v[2][1]*kw[3] + v[3][0]*kw[4] + v[3][1]*kw[5];
                c1v[ci][hh][cc] = fmaxf(fmaxf(a0, a1) + kb, 0.0f);
            }
        }
    }

    float A0 = 0.0f, A1 = 0.0f;
#pragma unroll
    for (int co2 = 0; co2 < 6; ++co2) {
        float c2v[4][2];
        float kb = kb2[co2];
#pragma unroll
        for (int r = 0; r < 4; ++r) {
#pragma unroll
            for (int c = 0; c < 2; ++c) {
                float p0 = 0.0f, p1 = 0.0f;
#pragma unroll
                for (int ci = 0; ci < 3; ++ci) {
                    const float* kw = k2w + (co2 * 3 + ci) * 6;
                    p0 += c1v[ci][2*r  ][c]*kw[0] + c1v[ci][2*r  ][c+1]*kw[1]
                        + c1v[ci][2*r+1][c]*kw[2] + c1v[ci][2*r+1][c+1]*kw[3]
                        + c1v[ci][2*r+2][c]*kw[4] + c1v[ci][2*r+2][c+1]*kw[5];
                    p1 += c1v[ci][2*r+1][c]*kw[0] + c1v[ci][2*r+1][c+1]*kw[1]
                        + c1v[ci][2*r+2][c]*kw[2] + c1v[ci][2*r+2][c+1]*kw[3]
                        + c1v[ci][2*r+3][c]*kw[4] + c1v[ci][2*r+3][c+1]*kw[5];
                }
                c2v[r][c] = fmaxf(fmaxf(p0, p1) + kb, 0.0f);
            }
        }
        const float* kw3 = k3w + (co * 6 + co2) * 6;
        A0 += c2v[0][0]*kw3[0] + c2v[0][1]*kw3[1] + c2v[1][0]*kw3[2]
            + c2v[1][1]*kw3[3] + c2v[2][0]*kw3[4] + c2v[2][1]*kw3[5];
        A1 += c2v[1][0]*kw3[0] + c2v[1][1]*kw3[1] + c2v[2][0]*kw3[2]
            + c2v[2][1]*kw3[3] + c2v[3][0]*kw3[4] + c2v[3][1]*kw3[5];
    }
    c3[t0] = fmaxf(fmaxf(A0, A1) + kb3[co], 0.0f);
}

// ---- kE: conv4 (redundant per block) into LDS, then FC1 rows (unchanged) ----
__global__ __launch_bounds__(256) void kE_conv4_fc1(
        const float* __restrict__ c3, const float* __restrict__ k4,
        const float* __restrict__ kb4, const float* __restrict__ fw1,
        const float* __restrict__ fb1, float* __restrict__ f1) {
    __shared__ __align__(16) float lc4[1680];
    const int Hin = 123, Win = 29, Wo = 28;
    float kb = kb4[0];
    for (int t0 = (int)threadIdx.x; t0 < 1680; t0 += 256) {
        int ow = t0 % Wo; int oh = t0 / Wo;
        float a0 = 0.0f, a1 = 0.0f;
#pragma unroll
        for (int ci = 0; ci < 3; ++ci) {
            const float* q = c3 + (ci * Hin + 2 * oh) * Win + ow;
            const float* wp = k4 + ci * 6;
            float r00 = q[0],     r01 = q[1];
            float r10 = q[Win],   r11 = q[Win+1];
            float r20 = q[2*Win], r21 = q[2*Win+1];
            float r30 = q[3*Win], r31 = q[3*Win+1];
            a0 += r00*wp[0] + r01*wp[1] + r10*wp[2] + r11*wp[3] + r20*wp[4] + r21*wp[5];
            a1 += r10*wp[0] + r11*wp[1] + r20*wp[2] + r21*wp[3] + r30*wp[4] + r31*wp[5];
        }
        float m = fmaxf(a0, a1) + kb;
        lc4[t0] = fmaxf(m, 0.0f);
    }
    __syncthreads();
    int wv = (int)threadIdx.x >> 6, lane = (int)threadIdx.x & 63;
    int o = blockIdx.x * 4 + wv;
    const float4* wr = (const float4*)(fw1 + (size_t)o * 1680);
    const float4* vv = (const float4*)lc4;
    float s = 0.0f;
    for (int i = lane; i < 420; i += 64) {
        float4 a = vv[i], ww = wr[i];
        s += a.x*ww.x + a.y*ww.y + a.z*ww.z + a.w*ww.w;
    }
#pragma unroll
    for (int off = 32; off > 0; off >>= 1) s += __shfl_down(s, off, 64);
    if (lane == 0) f1[o] = s + fb1[o];
}

// ---- kF: out[k] = sum_jc sum_i Mpart[jc][k][i]*f1[i] + fw3[k].fb2 + fb3[k].
//          One wave per output row; Mpart is L2-resident (4 MB just written). ----
__global__ __launch_bounds__(256) void kF_head(const float* __restrict__ f1,
        const float* __restrict__ Mpart, const float* __restrict__ fw3,
        const float* __restrict__ fb2, const float* __restrict__ fb3,
        float* __restrict__ out) {
    int wv = (int)threadIdx.x >> 6, lane = (int)threadIdx.x & 63;
    int k = blockIdx.x * 4 + wv;   // 16 blocks x 4 waves = 64 rows
    const float4* vv = (const float4*)f1;
    const float4* f3 = (const float4*)(fw3 + (size_t)k * 1024);
    const float4* bb = (const float4*)fb2;
    float s = 0.0f;
    // bias-propagation term: fw3[k] . fb2
#pragma unroll
    for (int i2 = 0; i2 < 4; ++i2) {
        float4 c = bb[lane + 64*i2], w3 = f3[lane + 64*i2];
        s += c.x*w3.x + c.y*w3.y + c.z*w3.z + c.w*w3.w;
    }
    // sum over 16 partials of M[k] . f1
    for (int jc = 0; jc < 16; ++jc) {
        const float4* Mr = (const float4*)(Mpart + (size_t)(jc * 64 + k) * 1024);
#pragma unroll
        for (int i2 = 0; i2 < 4; ++i2) {
            float4 a = vv[lane + 64*i2], ww = Mr[lane + 64*i2];
            s += a.x*ww.x + a.y*ww.y + a.z*ww.z + a.w*ww.w;
        }
    }
#pragma unroll
    for (int off = 32; off > 0; off >>= 1) s += __shfl_down(s, off, 64);
    if (lane == 0) out[k] = s + fb3[k];
}

extern "C" void kernel_launch(void* const* d_in, const int* in_sizes, int n_in,
                              void* d_out, int out_size, void* d_ws, size_t ws_size,
                              hipStream_t stream) {
    const float* x   = (const float*)d_in[0];
    const int*   ei  = (const int*)d_in[1];
    const float* W1  = (const float*)d_in[2];
    const float* b1  = (const float*)d_in[3];
    const float* W2  = (const float*)d_in[4];
    const float* b2  = (const float*)d_in[5];
    const float* k1  = (const float*)d_in[6];
    const float* kb1 = (const float*)d_in[7];
    const float* k2  = (const float*)d_in[8];
    const float* kb2 = (const float*)d_in[9];
    const float* k3  = (const float*)d_in[10];
    const float* kb3 = (const float*)d_in[11];
    const float* k4  = (const float*)d_in[12];
    const float* kb4 = (const float*)d_in[13];
    const float* fw1 = (const float*)d_in[14];
    const float* fb1 = (const float*)d_in[15];
    const float* fw2 = (const float*)d_in[16];
    const float* fb2 = (const float*)d_in[17];
    const float* fw3 = (const float*)d_in[18];
    const float* fb3 = (const float*)d_in[19];

    int n = in_sizes[0] / 6;       // 1000
    int E = in_sizes[1] / 2;       // 8000
    const int* row = ei;
    const int* col = ei + E;

    float* ws    = (float*)d_ws;
    float* deg   = ws;               // 1024
    float* agg1  = ws + 1024;        // 32000 (agg1+agg2 contiguous for kA zeroing)
    float* agg2  = agg1 + 32000;     // 32000
    float* Mpart = agg2 + 32000;     // 16*64*1024 = 1048576 (16B aligned)
    float* c3    = Mpart + 1048576;  // 10704 (padded)
    float* f1    = c3 + 10704;       // 1024 (16B aligned)

    const int B = 256;
    int st = (E + n) * 32;

    kA_prep<<<256, B, 0, stream>>>(col, fw2, fw3, deg, agg1, Mpart, n, E);
    kB_scatter1<<<(st + B - 1) / B, B, 0, stream>>>(x, W1, deg, row, col, agg1, E, n);
    kC_scatter2<<<(st + B - 1) / B, B, 0, stream>>>(agg1, b1, W2, deg, row, col, agg2, E, n);
    kD_c3<<<(3 * 123 * 29 + B - 1) / B, B, 0, stream>>>(agg2, b2, k1, kb1, k2, kb2, k3, kb3, c3);
    kE_conv4_fc1<<<256, B, 0, stream>>>(c3, k4, kb4, fw1, fb1, f1);
    kF_head<<<16, B, 0, stream>>>(f1, Mpart, fw3, fb2, fb3, (float*)d_out);
}

// Round 5
// 164.302 us; speedup vs baseline: 2.5339x; 1.0521x over previous
//
#include <hip/hip_runtime.h>

#define LEAKY(v) ((v) > 0.0f ? (v) : 0.2f * (v))

// ---- kA: zero agg1+agg2; deg by replicated scan; Mpart = j-split fw3@fw2 ----
__global__ __launch_bounds__(256) void kA_prep(
        const int* __restrict__ col, const float* __restrict__ fw2,
        const float* __restrict__ fw3, float* __restrict__ deg,
        float* __restrict__ aggs /*agg1,agg2 contiguous*/,
        float* __restrict__ Mpart, int n, int E) {
    int T = blockIdx.x * 256 + (int)threadIdx.x;
    if (T < 2 * n * 32) aggs[T] = 0.0f;
    int wave = T >> 6, lane = T & 63;
    if (wave < n) {
        int cnt = 0;
        for (int e = lane; e < E; e += 64) cnt += (col[e] == wave) ? 1 : 0;
#pragma unroll
        for (int off = 32; off > 0; off >>= 1) cnt += __shfl_down(cnt, off, 64);
        if (lane == 0) deg[wave] = (float)cnt;
    }
    {
        int jc = blockIdx.x >> 4;
        int it = (blockIdx.x & 15) * 64;
        int w  = (int)threadIdx.x >> 6;
        int i  = it + ((int)threadIdx.x & 63);
        int j0 = jc * 64;
        float acc[16];
#pragma unroll
        for (int kk = 0; kk < 16; ++kk) acc[kk] = 0.0f;
        const float* f3 = fw3 + (size_t)(w * 16) * 1024 + j0;
        for (int jj = 0; jj < 64; ++jj) {
            float wv = fw2[(size_t)(j0 + jj) * 1024 + i];
#pragma unroll
            for (int kk = 0; kk < 16; ++kk)
                acc[kk] += f3[(size_t)kk * 1024 + jj] * wv;
        }
#pragma unroll
        for (int kk = 0; kk < 16; ++kk)
            Mpart[(size_t)(jc * 64 + w * 16 + kk) * 1024 + i] = acc[kk];
    }
}

// ---- kB: scatter1 with x@W1 inlined ----
__global__ void kB_scatter1(const float* __restrict__ x, const float* __restrict__ W1,
        const float* __restrict__ deg, const int* __restrict__ row,
        const int* __restrict__ col, float* __restrict__ agg1, int E, int n) {
    int tid = blockIdx.x * blockDim.x + threadIdx.x;
    int total = (E + n) * 32;
    if (tid >= total) return;
    int e = tid >> 5, j = tid & 31;
    int r, c; float nrm;
    if (e < E) {
        r = row[e]; c = col[e];
        nrm = (1.0f / sqrtf(deg[r] + 1.0f)) * (1.0f / sqrtf(deg[c] + 1.0f));
    } else {
        r = c = e - E;
        nrm = 1.0f / (deg[r] + 1.0f);
    }
    float val = x[r*6+3] * W1[96+j] + x[r*6+4] * W1[128+j] + x[r*6+5] * W1[160+j];
    atomicAdd(&agg1[c * 32 + j], val * nrm);
}

// ---- kC: scatter2 with h2 = leaky(agg1+b1)@W2 recomputed per edge ----
__global__ void kC_scatter2(const float* __restrict__ agg1, const float* __restrict__ b1,
        const float* __restrict__ W2, const float* __restrict__ deg,
        const int* __restrict__ row, const int* __restrict__ col,
        float* __restrict__ agg2, int E, int n) {
    int tid = blockIdx.x * blockDim.x + threadIdx.x;
    int total = (E + n) * 32;
    if (tid >= total) return;
    int e = tid >> 5, j = tid & 31;
    int r, c; float nrm;
    if (e < E) {
        r = row[e]; c = col[e];
        nrm = (1.0f / sqrtf(deg[r] + 1.0f)) * (1.0f / sqrtf(deg[c] + 1.0f));
    } else {
        r = c = e - E;
        nrm = 1.0f / (deg[r] + 1.0f);
    }
    const float* a = agg1 + r * 32;
    float s = 0.0f;
#pragma unroll
    for (int f = 0; f < 32; ++f) {
        float v = a[f] + b1[f];
        v = LEAKY(v);
        s += v * W2[f * 32 + j];
    }
    atomicAdd(&agg2[c * 32 + j], s * nrm);
}

// ---- kD: conv1+conv2+conv3 as block-slab with LDS staging.
//          One block per c3 row (123 blocks). Fix for round-4's 42-block
//          latency-starved version (60us @ 1.7% occupancy, 72 cy/inst):
//          per-thread work 2000 -> ~450 ops, dependent-load chains replaced
//          by 2 LDS barriers. ----
__global__ __launch_bounds__(256) void kD_c3(const float* __restrict__ agg2,
        const float* __restrict__ b2,
        const float* __restrict__ k1w, const float* __restrict__ kb1,
        const float* __restrict__ k2w, const float* __restrict__ kb2,
        const float* __restrict__ k3w, const float* __restrict__ kb3,
        float* __restrict__ c3) {
    __shared__ float lc1[3][10][31];   // c1 rows 4*oh3 .. 4*oh3+9
    __shared__ float lc2[6][4][30];    // c2 rows 2*oh3 .. 2*oh3+3
    const int oh3 = blockIdx.x;        // 0..122
    const int tid = (int)threadIdx.x;

    // Stage 1: c1 slab (930 values, <=4 per thread). c1[ci][hh][ow1] from agg2.
    for (int idx = tid; idx < 930; idx += 256) {
        int ci = idx / 310, rem = idx % 310;
        int hh = rem / 31, ow1 = rem % 31;
        int r0 = (4 * oh3 + hh) * 2;           // agg2 base row (max 997)
        const float* kw = k1w + ci * 6;
        float v[4][2];
#pragma unroll
        for (int rr = 0; rr < 4; ++rr)
#pragma unroll
            for (int dc = 0; dc < 2; ++dc) {
                float u = agg2[(r0 + rr) * 32 + ow1 + dc] + b2[ow1 + dc];
                v[rr][dc] = LEAKY(u);
            }
        float a0 = v[0][0]*kw[0] + v[0][1]*kw[1] + v[1][0]*kw[2]
                 + v[1][1]*kw[3] + v[2][0]*kw[4] + v[2][1]*kw[5];
        float a1 = v[1][0]*kw[0] + v[1][1]*kw[1] + v[2][0]*kw[2]
                 + v[2][1]*kw[3] + v[3][0]*kw[4] + v[3][1]*kw[5];
        lc1[ci][hh][ow1] = fmaxf(fmaxf(a0, a1) + kb1[ci], 0.0f);
    }
    __syncthreads();

    // Stage 2: c2 slab (720 values, <=3 per thread). c2[co2][r][ow2] from lc1.
    for (int idx = tid; idx < 720; idx += 256) {
        int co2 = idx / 120, rem = idx % 120;
        int r = rem / 30, ow2 = rem % 30;
        float p0 = 0.0f, p1 = 0.0f;
#pragma unroll
        for (int ci = 0; ci < 3; ++ci) {
            const float* kw = k2w + (co2 * 3 + ci) * 6;
            const float* q0 = &lc1[ci][2*r][ow2];
            float r00 = q0[0],      r01 = q0[1];
            float r10 = q0[31],     r11 = q0[32];
            float r20 = q0[62],     r21 = q0[63];
            float r30 = q0[93],     r31 = q0[94];
            p0 += r00*kw[0] + r01*kw[1] + r10*kw[2] + r11*kw[3] + r20*kw[4] + r21*kw[5];
            p1 += r10*kw[0] + r11*kw[1] + r20*kw[2] + r21*kw[3] + r30*kw[4] + r31*kw[5];
        }
        lc2[co2][r][ow2] = fmaxf(fmaxf(p0, p1) + kb2[co2], 0.0f);
    }
    __syncthreads();

    // Stage 3: one c3 row = 87 outputs (threads 0..86).
    if (tid < 87) {
        int co = tid / 29, ow3 = tid % 29;
        float A0 = 0.0f, A1 = 0.0f;
#pragma unroll
        for (int co2 = 0; co2 < 6; ++co2) {
            const float* kw3 = k3w + (co * 6 + co2) * 6;
            const float* q0 = &lc2[co2][0][ow3];
            float r00 = q0[0],      r01 = q0[1];
            float r10 = q0[30],     r11 = q0[31];
            float r20 = q0[60],     r21 = q0[61];
            float r30 = q0[90],     r31 = q0[91];
            A0 += r00*kw3[0] + r01*kw3[1] + r10*kw3[2] + r11*kw3[3] + r20*kw3[4] + r21*kw3[5];
            A1 += r10*kw3[0] + r11*kw3[1] + r20*kw3[2] + r21*kw3[3] + r30*kw3[4] + r31*kw3[5];
        }
        c3[(co * 123 + oh3) * 29 + ow3] = fmaxf(fmaxf(A0, A1) + kb3[co], 0.0f);
    }
}

// ---- kE: conv4 (redundant per block) into LDS, then FC1 rows (unchanged) ----
__global__ __launch_bounds__(256) void kE_conv4_fc1(
        const float* __restrict__ c3, const float* __restrict__ k4,
        const float* __restrict__ kb4, const float* __restrict__ fw1,
        const float* __restrict__ fb1, float* __restrict__ f1) {
    __shared__ __align__(16) float lc4[1680];
    const int Hin = 123, Win = 29, Wo = 28;
    float kb = kb4[0];
    for (int t0 = (int)threadIdx.x; t0 < 1680; t0 += 256) {
        int ow = t0 % Wo; int oh = t0 / Wo;
        float a0 = 0.0f, a1 = 0.0f;
#pragma unroll
        for (int ci = 0; ci < 3; ++ci) {
            const float* q = c3 + (ci * Hin + 2 * oh) * Win + ow;
            const float* wp = k4 + ci * 6;
            float r00 = q[0],     r01 = q[1];
            float r10 = q[Win],   r11 = q[Win+1];
            float r20 = q[2*Win], r21 = q[2*Win+1];
            float r30 = q[3*Win], r31 = q[3*Win+1];
            a0 += r00*wp[0] + r01*wp[1] + r10*wp[2] + r11*wp[3] + r20*wp[4] + r21*wp[5];
            a1 += r10*wp[0] + r11*wp[1] + r20*wp[2] + r21*wp[3] + r30*wp[4] + r31*wp[5];
        }
        float m = fmaxf(a0, a1) + kb;
        lc4[t0] = fmaxf(m, 0.0f);
    }
    __syncthreads();
    int wv = (int)threadIdx.x >> 6, lane = (int)threadIdx.x & 63;
    int o = blockIdx.x * 4 + wv;
    const float4* wr = (const float4*)(fw1 + (size_t)o * 1680);
    const float4* vv = (const float4*)lc4;
    float s = 0.0f;
    for (int i = lane; i < 420; i += 64) {
        float4 a = vv[i], ww = wr[i];
        s += a.x*ww.x + a.y*ww.y + a.z*ww.z + a.w*ww.w;
    }
#pragma unroll
    for (int off = 32; off > 0; off >>= 1) s += __shfl_down(s, off, 64);
    if (lane == 0) f1[o] = s + fb1[o];
}

// ---- kF: out[k] = sum_jc Mpart[jc][k].f1 + fw3[k].fb2 + fb3[k] (unchanged) ----
__global__ __launch_bounds__(256) void kF_head(const float* __restrict__ f1,
        const float* __restrict__ Mpart, const float* __restrict__ fw3,
        const float* __restrict__ fb2, const float* __restrict__ fb3,
        float* __restrict__ out) {
    int wv = (int)threadIdx.x >> 6, lane = (int)threadIdx.x & 63;
    int k = blockIdx.x * 4 + wv;
    const float4* vv = (const float4*)f1;
    const float4* f3 = (const float4*)(fw3 + (size_t)k * 1024);
    const float4* bb = (const float4*)fb2;
    float s = 0.0f;
#pragma unroll
    for (int i2 = 0; i2 < 4; ++i2) {
        float4 c = bb[lane + 64*i2], w3 = f3[lane + 64*i2];
        s += c.x*w3.x + c.y*w3.y + c.z*w3.z + c.w*w3.w;
    }
    for (int jc = 0; jc < 16; ++jc) {
        const float4* Mr = (const float4*)(Mpart + (size_t)(jc * 64 + k) * 1024);
#pragma unroll
        for (int i2 = 0; i2 < 4; ++i2) {
            float4 a = vv[lane + 64*i2], ww = Mr[lane + 64*i2];
            s += a.x*ww.x + a.y*ww.y + a.z*ww.z + a.w*ww.w;
        }
    }
#pragma unroll
    for (int off = 32; off > 0; off >>= 1) s += __shfl_down(s, off, 64);
    if (lane == 0) out[k] = s + fb3[k];
}

extern "C" void kernel_launch(void* const* d_in, const int* in_sizes, int n_in,
                              void* d_out, int out_size, void* d_ws, size_t ws_size,
                              hipStream_t stream) {
    const float* x   = (const float*)d_in[0];
    const int*   ei  = (const int*)d_in[1];
    const float* W1  = (const float*)d_in[2];
    const float* b1  = (const float*)d_in[3];
    const float* W2  = (const float*)d_in[4];
    const float* b2  = (const float*)d_in[5];
    const float* k1  = (const float*)d_in[6];
    const float* kb1 = (const float*)d_in[7];
    const float* k2  = (const float*)d_in[8];
    const float* kb2 = (const float*)d_in[9];
    const float* k3  = (const float*)d_in[10];
    const float* kb3 = (const float*)d_in[11];
    const float* k4  = (const float*)d_in[12];
    const float* kb4 = (const float*)d_in[13];
    const float* fw1 = (const float*)d_in[14];
    const float* fb1 = (const float*)d_in[15];
    const float* fw2 = (const float*)d_in[16];
    const float* fb2 = (const float*)d_in[17];
    const float* fw3 = (const float*)d_in[18];
    const float* fb3 = (const float*)d_in[19];

    int n = in_sizes[0] / 6;       // 1000
    int E = in_sizes[1] / 2;       // 8000
    const int* row = ei;
    const int* col = ei + E;

    float* ws    = (float*)d_ws;
    float* deg   = ws;               // 1024
    float* agg1  = ws + 1024;        // 32000 (agg1+agg2 contiguous for kA zeroing)
    float* agg2  = agg1 + 32000;     // 32000
    float* Mpart = agg2 + 32000;     // 16*64*1024 = 1048576 (16B aligned)
    float* c3    = Mpart + 1048576;  // 10704 (padded)
    float* f1    = c3 + 10704;       // 1024 (16B aligned)

    const int B = 256;
    int st = (E + n) * 32;

    kA_prep<<<256, B, 0, stream>>>(col, fw2, fw3, deg, agg1, Mpart, n, E);
    kB_scatter1<<<(st + B - 1) / B, B, 0, stream>>>(x, W1, deg, row, col, agg1, E, n);
    kC_scatter2<<<(st + B - 1) / B, B, 0, stream>>>(agg1, b1, W2, deg, row, col, agg2, E, n);
    kD_c3<<<123, B, 0, stream>>>(agg2, b2, k1, kb1, k2, kb2, k3, kb3, c3);
    kE_conv4_fc1<<<256, B, 0, stream>>>(c3, k4, kb4, fw1, fb1, f1);
    kF_head<<<16, B, 0, stream>>>(f1, Mpart, fw3, fb2, fb3, (float*)d_out);
}

// Round 6
// 156.747 us; speedup vs baseline: 2.6560x; 1.0482x over previous
//
#include <hip/hip_runtime.h>

#define LEAKY(v) ((v) > 0.0f ? (v) : 0.2f * (v))

// ---- kA: zero agg1+agg2+out; degree via block-per-node coalesced count.
//          (Round-5's Mpart GEMM removed: it was 60x the work of direct FC2
//          and latency-bound at 44us. FC2+FC3 now live in kF_fc23.) ----
__global__ __launch_bounds__(256) void kA_prep(
        const int* __restrict__ col, float* __restrict__ deg,
        float* __restrict__ aggs /*agg1,agg2 contiguous*/,
        float* __restrict__ outz, int n, int E) {
    int T = blockIdx.x * 256 + (int)threadIdx.x;
    int nz = 2 * n * 32;
    if (T < nz) aggs[T] = 0.0f;
    else if (T < nz + 64) outz[T - nz] = 0.0f;

    // degree: one block per node, 256 threads scan col (32KB, L1/L2-hot)
    int b = blockIdx.x;
    if (b < n) {
        __shared__ int wsum[4];
        int tid = (int)threadIdx.x;
        int cnt = 0;
        for (int e = tid; e < E; e += 256) cnt += (col[e] == b) ? 1 : 0;
#pragma unroll
        for (int off = 32; off > 0; off >>= 1) cnt += __shfl_down(cnt, off, 64);
        if ((tid & 63) == 0) wsum[tid >> 6] = cnt;
        __syncthreads();
        if (tid == 0) deg[b] = (float)(wsum[0] + wsum[1] + wsum[2] + wsum[3]);
    }
}

// ---- kB: scatter1 with x@W1 inlined (unchanged, verified) ----
__global__ void kB_scatter1(const float* __restrict__ x, const float* __restrict__ W1,
        const float* __restrict__ deg, const int* __restrict__ row,
        const int* __restrict__ col, float* __restrict__ agg1, int E, int n) {
    int tid = blockIdx.x * blockDim.x + threadIdx.x;
    int total = (E + n) * 32;
    if (tid >= total) return;
    int e = tid >> 5, j = tid & 31;
    int r, c; float nrm;
    if (e < E) {
        r = row[e]; c = col[e];
        nrm = (1.0f / sqrtf(deg[r] + 1.0f)) * (1.0f / sqrtf(deg[c] + 1.0f));
    } else {
        r = c = e - E;
        nrm = 1.0f / (deg[r] + 1.0f);
    }
    float val = x[r*6+3] * W1[96+j] + x[r*6+4] * W1[128+j] + x[r*6+5] * W1[160+j];
    atomicAdd(&agg1[c * 32 + j], val * nrm);
}

// ---- kC: scatter2 with h2 = leaky(agg1+b1)@W2 recomputed per edge (unchanged) ----
__global__ void kC_scatter2(const float* __restrict__ agg1, const float* __restrict__ b1,
        const float* __restrict__ W2, const float* __restrict__ deg,
        const int* __restrict__ row, const int* __restrict__ col,
        float* __restrict__ agg2, int E, int n) {
    int tid = blockIdx.x * blockDim.x + threadIdx.x;
    int total = (E + n) * 32;
    if (tid >= total) return;
    int e = tid >> 5, j = tid & 31;
    int r, c; float nrm;
    if (e < E) {
        r = row[e]; c = col[e];
        nrm = (1.0f / sqrtf(deg[r] + 1.0f)) * (1.0f / sqrtf(deg[c] + 1.0f));
    } else {
        r = c = e - E;
        nrm = 1.0f / (deg[r] + 1.0f);
    }
    const float* a = agg1 + r * 32;
    float s = 0.0f;
#pragma unroll
    for (int f = 0; f < 32; ++f) {
        float v = a[f] + b1[f];
        v = LEAKY(v);
        s += v * W2[f * 32 + j];
    }
    atomicAdd(&agg2[c * 32 + j], s * nrm);
}

// ---- kD: conv1+conv2+conv3 block-slab with LDS staging (unchanged, verified) ----
__global__ __launch_bounds__(256) void kD_c3(const float* __restrict__ agg2,
        const float* __restrict__ b2,
        const float* __restrict__ k1w, const float* __restrict__ kb1,
        const float* __restrict__ k2w, const float* __restrict__ kb2,
        const float* __restrict__ k3w, const float* __restrict__ kb3,
        float* __restrict__ c3) {
    __shared__ float lc1[3][10][31];
    __shared__ float lc2[6][4][30];
    const int oh3 = blockIdx.x;
    const int tid = (int)threadIdx.x;

    for (int idx = tid; idx < 930; idx += 256) {
        int ci = idx / 310, rem = idx % 310;
        int hh = rem / 31, ow1 = rem % 31;
        int r0 = (4 * oh3 + hh) * 2;
        const float* kw = k1w + ci * 6;
        float v[4][2];
#pragma unroll
        for (int rr = 0; rr < 4; ++rr)
#pragma unroll
            for (int dc = 0; dc < 2; ++dc) {
                float u = agg2[(r0 + rr) * 32 + ow1 + dc] + b2[ow1 + dc];
                v[rr][dc] = LEAKY(u);
            }
        float a0 = v[0][0]*kw[0] + v[0][1]*kw[1] + v[1][0]*kw[2]
                 + v[1][1]*kw[3] + v[2][0]*kw[4] + v[2][1]*kw[5];
        float a1 = v[1][0]*kw[0] + v[1][1]*kw[1] + v[2][0]*kw[2]
                 + v[2][1]*kw[3] + v[3][0]*kw[4] + v[3][1]*kw[5];
        lc1[ci][hh][ow1] = fmaxf(fmaxf(a0, a1) + kb1[ci], 0.0f);
    }
    __syncthreads();

    for (int idx = tid; idx < 720; idx += 256) {
        int co2 = idx / 120, rem = idx % 120;
        int r = rem / 30, ow2 = rem % 30;
        float p0 = 0.0f, p1 = 0.0f;
#pragma unroll
        for (int ci = 0; ci < 3; ++ci) {
            const float* kw = k2w + (co2 * 3 + ci) * 6;
            const float* q0 = &lc1[ci][2*r][ow2];
            float r00 = q0[0],      r01 = q0[1];
            float r10 = q0[31],     r11 = q0[32];
            float r20 = q0[62],     r21 = q0[63];
            float r30 = q0[93],     r31 = q0[94];
            p0 += r00*kw[0] + r01*kw[1] + r10*kw[2] + r11*kw[3] + r20*kw[4] + r21*kw[5];
            p1 += r10*kw[0] + r11*kw[1] + r20*kw[2] + r21*kw[3] + r30*kw[4] + r31*kw[5];
        }
        lc2[co2][r][ow2] = fmaxf(fmaxf(p0, p1) + kb2[co2], 0.0f);
    }
    __syncthreads();

    if (tid < 87) {
        int co = tid / 29, ow3 = tid % 29;
        float A0 = 0.0f, A1 = 0.0f;
#pragma unroll
        for (int co2 = 0; co2 < 6; ++co2) {
            const float* kw3 = k3w + (co * 6 + co2) * 6;
            const float* q0 = &lc2[co2][0][ow3];
            float r00 = q0[0],      r01 = q0[1];
            float r10 = q0[30],     r11 = q0[31];
            float r20 = q0[60],     r21 = q0[61];
            float r30 = q0[90],     r31 = q0[91];
            A0 += r00*kw3[0] + r01*kw3[1] + r10*kw3[2] + r11*kw3[3] + r20*kw3[4] + r21*kw3[5];
            A1 += r10*kw3[0] + r11*kw3[1] + r20*kw3[2] + r21*kw3[3] + r30*kw3[4] + r31*kw3[5];
        }
        c3[(co * 123 + oh3) * 29 + ow3] = fmaxf(fmaxf(A0, A1) + kb3[co], 0.0f);
    }
}

// ---- kE: conv4 (redundant per block) into LDS, then FC1 rows (unchanged) ----
__global__ __launch_bounds__(256) void kE_conv4_fc1(
        const float* __restrict__ c3, const float* __restrict__ k4,
        const float* __restrict__ kb4, const float* __restrict__ fw1,
        const float* __restrict__ fb1, float* __restrict__ f1) {
    __shared__ __align__(16) float lc4[1680];
    const int Hin = 123, Win = 29, Wo = 28;
    float kb = kb4[0];
    for (int t0 = (int)threadIdx.x; t0 < 1680; t0 += 256) {
        int ow = t0 % Wo; int oh = t0 / Wo;
        float a0 = 0.0f, a1 = 0.0f;
#pragma unroll
        for (int ci = 0; ci < 3; ++ci) {
            const float* q = c3 + (ci * Hin + 2 * oh) * Win + ow;
            const float* wp = k4 + ci * 6;
            float r00 = q[0],     r01 = q[1];
            float r10 = q[Win],   r11 = q[Win+1];
            float r20 = q[2*Win], r21 = q[2*Win+1];
            float r30 = q[3*Win], r31 = q[3*Win+1];
            a0 += r00*wp[0] + r01*wp[1] + r10*wp[2] + r11*wp[3] + r20*wp[4] + r21*wp[5];
            a1 += r10*wp[0] + r11*wp[1] + r20*wp[2] + r21*wp[3] + r30*wp[4] + r31*wp[5];
        }
        float m = fmaxf(a0, a1) + kb;
        lc4[t0] = fmaxf(m, 0.0f);
    }
    __syncthreads();
    int wv = (int)threadIdx.x >> 6, lane = (int)threadIdx.x & 63;
    int o = blockIdx.x * 4 + wv;
    const float4* wr = (const float4*)(fw1 + (size_t)o * 1680);
    const float4* vv = (const float4*)lc4;
    float s = 0.0f;
    for (int i = lane; i < 420; i += 64) {
        float4 a = vv[i], ww = wr[i];
        s += a.x*ww.x + a.y*ww.y + a.z*ww.z + a.w*ww.w;
    }
#pragma unroll
    for (int off = 32; off > 0; off >>= 1) s += __shfl_down(s, off, 64);
    if (lane == 0) f1[o] = s + fb1[o];
}

// ---- kF: FC2+FC3 in one dispatch. 64 blocks, block b owns j in [16b,16b+16):
//          computes f2[j] = f1.fw2[j] + fb2[j] (coalesced float4), then
//          atomicAdds its partial of out[k] = sum_j fw3[k][j]*f2[j].
//          out pre-zeroed in kA; block 0 adds fb3. ----
__global__ __launch_bounds__(256) void kF_fc23(const float* __restrict__ f1,
        const float* __restrict__ fw2, const float* __restrict__ fb2,
        const float* __restrict__ fw3, const float* __restrict__ fb3,
        float* __restrict__ out) {
    __shared__ float f2loc[16];
    int wv = (int)threadIdx.x >> 6, lane = (int)threadIdx.x & 63;
    int jbase = blockIdx.x * 16;
    const float4* vv = (const float4*)f1;
    // wave wv computes j = jbase + 4*wv + q
    for (int q = 0; q < 4; ++q) {
        int j = jbase + wv * 4 + q;
        const float4* wr = (const float4*)(fw2 + (size_t)j * 1024);
        float s = 0.0f;
#pragma unroll
        for (int i2 = 0; i2 < 4; ++i2) {
            float4 a = vv[lane + 64*i2], ww = wr[lane + 64*i2];
            s += a.x*ww.x + a.y*ww.y + a.z*ww.z + a.w*ww.w;
        }
#pragma unroll
        for (int off = 32; off > 0; off >>= 1) s += __shfl_down(s, off, 64);
        if (lane == 0) f2loc[wv * 4 + q] = s + fb2[j];
    }
    __syncthreads();
    // wave wv handles k = 16*wv .. 16*wv+15; lanes 0..15 hold one j-term each
    for (int kk = 0; kk < 16; ++kk) {
        int k = wv * 16 + kk;
        float v = 0.0f;
        if (lane < 16) v = fw3[(size_t)k * 1024 + jbase + lane] * f2loc[lane];
#pragma unroll
        for (int off = 8; off > 0; off >>= 1) v += __shfl_down(v, off, 16);
        if (lane == 0) {
            if (blockIdx.x == 0) v += fb3[k];
            atomicAdd(&out[k], v);
        }
    }
}

extern "C" void kernel_launch(void* const* d_in, const int* in_sizes, int n_in,
                              void* d_out, int out_size, void* d_ws, size_t ws_size,
                              hipStream_t stream) {
    const float* x   = (const float*)d_in[0];
    const int*   ei  = (const int*)d_in[1];
    const float* W1  = (const float*)d_in[2];
    const float* b1  = (const float*)d_in[3];
    const float* W2  = (const float*)d_in[4];
    const float* b2  = (const float*)d_in[5];
    const float* k1  = (const float*)d_in[6];
    const float* kb1 = (const float*)d_in[7];
    const float* k2  = (const float*)d_in[8];
    const float* kb2 = (const float*)d_in[9];
    const float* k3  = (const float*)d_in[10];
    const float* kb3 = (const float*)d_in[11];
    const float* k4  = (const float*)d_in[12];
    const float* kb4 = (const float*)d_in[13];
    const float* fw1 = (const float*)d_in[14];
    const float* fb1 = (const float*)d_in[15];
    const float* fw2 = (const float*)d_in[16];
    const float* fb2 = (const float*)d_in[17];
    const float* fw3 = (const float*)d_in[18];
    const float* fb3 = (const float*)d_in[19];

    int n = in_sizes[0] / 6;       // 1000
    int E = in_sizes[1] / 2;       // 8000
    const int* row = ei;
    const int* col = ei + E;

    float* ws   = (float*)d_ws;
    float* deg  = ws;              // 1024 (written fully by kA deg scan)
    float* agg1 = ws + 1024;       // 32000 (agg1+agg2 contiguous, zeroed in kA)
    float* agg2 = agg1 + 32000;    // 32000
    float* c3   = agg2 + 32000;    // 10704 (padded, 16B aligned)
    float* f1   = c3 + 10704;      // 1024 (16B aligned)

    const int B = 256;
    int st = (E + n) * 32;

    kA_prep<<<n, B, 0, stream>>>(col, deg, agg1, (float*)d_out, n, E);
    kB_scatter1<<<(st + B - 1) / B, B, 0, stream>>>(x, W1, deg, row, col, agg1, E, n);
    kC_scatter2<<<(st + B - 1) / B, B, 0, stream>>>(agg1, b1, W2, deg, row, col, agg2, E, n);
    kD_c3<<<123, B, 0, stream>>>(agg2, b2, k1, kb1, k2, kb2, k3, kb3, c3);
    kE_conv4_fc1<<<256, B, 0, stream>>>(c3, k4, kb4, fw1, fb1, f1);
    kF_fc23<<<64, B, 0, stream>>>(f1, fw2, fb2, fw3, fb3, (float*)d_out);
}

// Round 9
// 155.803 us; speedup vs baseline: 2.6721x; 1.0061x over previous
//
#include <hip/hip_runtime.h>

#define LEAKY(v) ((v) > 0.0f ? (v) : 0.2f * (v))

// ---- kA: zero agg1+agg2 (+f1, +out); degree via block-per-node count ----
__global__ __launch_bounds__(256) void kA_prep(
        const int* __restrict__ col, float* __restrict__ deg,
        float* __restrict__ aggs /*agg1,agg2 contiguous*/,
        float* __restrict__ f1z, float* __restrict__ outz, int n, int E) {
    int T = blockIdx.x * 256 + (int)threadIdx.x;
    if (T < 64000) aggs[T] = 0.0f;
    else if (T < 65024) f1z[T - 64000] = 0.0f;
    else if (T < 65088) outz[T - 65024] = 0.0f;

    // degree: one block per node, 256 threads scan col (32KB, L2-hot)
    int b = blockIdx.x;
    if (b < n) {
        __shared__ int wsum[4];
        int tid = (int)threadIdx.x;
        int cnt = 0;
        for (int e = tid; e < E; e += 256) cnt += (col[e] == b) ? 1 : 0;
#pragma unroll
        for (int off = 32; off > 0; off >>= 1) cnt += __shfl_down(cnt, off, 64);
        if ((tid & 63) == 0) wsum[tid >> 6] = cnt;
        __syncthreads();
        if (tid == 0) deg[b] = (float)(wsum[0] + wsum[1] + wsum[2] + wsum[3]);
    }
}

// ---- kB: scatter1 with x@W1 inlined (unchanged, verified) ----
__global__ void kB_scatter1(const float* __restrict__ x, const float* __restrict__ W1,
        const float* __restrict__ deg, const int* __restrict__ row,
        const int* __restrict__ col, float* __restrict__ agg1, int E, int n) {
    int tid = blockIdx.x * blockDim.x + threadIdx.x;
    int total = (E + n) * 32;
    if (tid >= total) return;
    int e = tid >> 5, j = tid & 31;
    int r, c; float nrm;
    if (e < E) {
        r = row[e]; c = col[e];
        nrm = (1.0f / sqrtf(deg[r] + 1.0f)) * (1.0f / sqrtf(deg[c] + 1.0f));
    } else {
        r = c = e - E;
        nrm = 1.0f / (deg[r] + 1.0f);
    }
    float val = x[r*6+3] * W1[96+j] + x[r*6+4] * W1[128+j] + x[r*6+5] * W1[160+j];
    atomicAdd(&agg1[c * 32 + j], val * nrm);
}

// ---- kC: scatter2 with h2 = leaky(agg1+b1)@W2 recomputed per edge (unchanged) ----
__global__ void kC_scatter2(const float* __restrict__ agg1, const float* __restrict__ b1,
        const float* __restrict__ W2, const float* __restrict__ deg,
        const int* __restrict__ row, const int* __restrict__ col,
        float* __restrict__ agg2, int E, int n) {
    int tid = blockIdx.x * blockDim.x + threadIdx.x;
    int total = (E + n) * 32;
    if (tid >= total) return;
    int e = tid >> 5, j = tid & 31;
    int r, c; float nrm;
    if (e < E) {
        r = row[e]; c = col[e];
        nrm = (1.0f / sqrtf(deg[r] + 1.0f)) * (1.0f / sqrtf(deg[c] + 1.0f));
    } else {
        r = c = e - E;
        nrm = 1.0f / (deg[r] + 1.0f);
    }
    const float* a = agg1 + r * 32;
    float s = 0.0f;
#pragma unroll
    for (int f = 0; f < 32; ++f) {
        float v = a[f] + b1[f];
        v = LEAKY(v);
        s += v * W2[f * 32 + j];
    }
    atomicAdd(&agg2[c * 32 + j], s * nrm);
}

// ---- kD: conv1..conv4 + FC1-partial, one dispatch.
//          blockIdx = 4*b + q: b in [0,60) = conv4-pooled row, q = o-quarter.
//          Block computes c1[3][22][31] -> c2[6][10][30] -> c3[3][4][29]
//          -> c4row[28] in LDS (2.4x redundant conv work, ~30M ops total),
//          then f1[o] += fw1[o][28b..28b+27] . c4row for its 256 o's. ----
__global__ __launch_bounds__(256) void kD_conv_fc1(const float* __restrict__ agg2,
        const float* __restrict__ b2,
        const float* __restrict__ k1w, const float* __restrict__ kb1,
        const float* __restrict__ k2w, const float* __restrict__ kb2,
        const float* __restrict__ k3w, const float* __restrict__ kb3,
        const float* __restrict__ k4w, const float* __restrict__ kb4,
        const float* __restrict__ fw1, float* __restrict__ f1) {
    __shared__ float lc1[3][22][31];
    __shared__ float lc2[6][10][30];
    __shared__ float lc3[3][4][29];
    __shared__ __align__(16) float lc4[28];
    const int b   = blockIdx.x >> 2;       // 0..59
    const int qo  = blockIdx.x & 3;        // o-quarter
    const int tid = (int)threadIdx.x;

    // Stage A: c1 slab rows 8b..8b+21 (2046 values, 8/thread)
    for (int idx = tid; idx < 2046; idx += 256) {
        int ci = idx / 682, rem = idx % 682;
        int hh = rem / 31, ow1 = rem % 31;
        int r0 = 16 * b + 2 * hh;                       // agg2 base row (max 989)
        const float* kw = k1w + ci * 6;
        float v[4][2];
#pragma unroll
        for (int rr = 0; rr < 4; ++rr)
#pragma unroll
            for (int dc = 0; dc < 2; ++dc) {
                float u = agg2[(r0 + rr) * 32 + ow1 + dc] + b2[ow1 + dc];
                v[rr][dc] = LEAKY(u);
            }
        float a0 = v[0][0]*kw[0] + v[0][1]*kw[1] + v[1][0]*kw[2]
                 + v[1][1]*kw[3] + v[2][0]*kw[4] + v[2][1]*kw[5];
        float a1 = v[1][0]*kw[0] + v[1][1]*kw[1] + v[2][0]*kw[2]
                 + v[2][1]*kw[3] + v[3][0]*kw[4] + v[3][1]*kw[5];
        lc1[ci][hh][ow1] = fmaxf(fmaxf(a0, a1) + kb1[ci], 0.0f);
    }
    __syncthreads();

    // Stage B: c2 slab rows 4b..4b+9 (1800 values, 8/thread)
    for (int idx = tid; idx < 1800; idx += 256) {
        int co2 = idx / 300, rem = idx % 300;
        int rr = rem / 30, ow2 = rem % 30;
        float p0 = 0.0f, p1 = 0.0f;
#pragma unroll
        for (int ci = 0; ci < 3; ++ci) {
            const float* kw = k2w + (co2 * 3 + ci) * 6;
            const float* q0 = &lc1[ci][2*rr][ow2];
            float r00 = q0[0],      r01 = q0[1];
            float r10 = q0[31],     r11 = q0[32];
            float r20 = q0[62],     r21 = q0[63];
            float r30 = q0[93],     r31 = q0[94];
            p0 += r00*kw[0] + r01*kw[1] + r10*kw[2] + r11*kw[3] + r20*kw[4] + r21*kw[5];
            p1 += r10*kw[0] + r11*kw[1] + r20*kw[2] + r21*kw[3] + r30*kw[4] + r31*kw[5];
        }
        lc2[co2][rr][ow2] = fmaxf(fmaxf(p0, p1) + kb2[co2], 0.0f);
    }
    __syncthreads();

    // Stage C: c3 slab rows 2b..2b+3 (348 values, 2/thread)
    for (int idx = tid; idx < 348; idx += 256) {
        int co = idx / 116, rem = idx % 116;
        int rr3 = rem / 29, ow3 = rem % 29;
        float A0 = 0.0f, A1 = 0.0f;
#pragma unroll
        for (int co2 = 0; co2 < 6; ++co2) {
            const float* kw3 = k3w + (co * 6 + co2) * 6;
            const float* q0 = &lc2[co2][2*rr3][ow3];
            float r00 = q0[0],      r01 = q0[1];
            float r10 = q0[30],     r11 = q0[31];
            float r20 = q0[60],     r21 = q0[61];
            float r30 = q0[90],     r31 = q0[91];
            A0 += r00*kw3[0] + r01*kw3[1] + r10*kw3[2] + r11*kw3[3] + r20*kw3[4] + r21*kw3[5];
            A1 += r10*kw3[0] + r11*kw3[1] + r20*kw3[2] + r21*kw3[3] + r30*kw3[4] + r31*kw3[5];
        }
        lc3[co][rr3][ow3] = fmaxf(fmaxf(A0, A1) + kb3[co], 0.0f);
    }
    __syncthreads();

    // Stage D: c4 row b (28 values, threads 0..27)
    if (tid < 28) {
        float a0 = 0.0f, a1 = 0.0f;
#pragma unroll
        for (int ci = 0; ci < 3; ++ci) {
            const float* wp = k4w + ci * 6;
            const float* q = &lc3[ci][0][tid];
            float r00 = q[0],   r01 = q[1];
            float r10 = q[29],  r11 = q[30];
            float r20 = q[58],  r21 = q[59];
            float r30 = q[87],  r31 = q[88];
            a0 += r00*wp[0] + r01*wp[1] + r10*wp[2] + r11*wp[3] + r20*wp[4] + r21*wp[5];
            a1 += r10*wp[0] + r11*wp[1] + r20*wp[2] + r21*wp[3] + r30*wp[4] + r31*wp[5];
        }
        lc4[tid] = fmaxf(fmaxf(a0, a1) + kb4[0], 0.0f);
    }
    __syncthreads();

    // Stage E: FC1 partial — o = qo*256 + tid, j-range [28b, 28b+28)
    {
        int o = qo * 256 + tid;
        const float4* wr = (const float4*)(fw1 + (size_t)o * 1680 + b * 28);
        const float4* cv = (const float4*)lc4;
        float s = 0.0f;
#pragma unroll
        for (int i = 0; i < 7; ++i) {
            float4 w4 = wr[i], c4 = cv[i];
            s += w4.x*c4.x + w4.y*c4.y + w4.z*c4.z + w4.w*c4.w;
        }
        atomicAdd(&f1[o], s);
    }
}

// ---- kF: FC2+FC3, fb1 folded: f2[j] = (f1+fb1).fw2[j] + fb2[j];
//          out[k] += fw3[k][jchunk].f2chunk (out pre-zeroed in kA). ----
__global__ __launch_bounds__(256) void kF_fc23(const float* __restrict__ f1,
        const float* __restrict__ fb1,
        const float* __restrict__ fw2, const float* __restrict__ fb2,
        const float* __restrict__ fw3, const float* __restrict__ fb3,
        float* __restrict__ out) {
    __shared__ float f2loc[16];
    int wv = (int)threadIdx.x >> 6, lane = (int)threadIdx.x & 63;
    int jbase = blockIdx.x * 16;
    const float4* vv = (const float4*)f1;
    const float4* bb1 = (const float4*)fb1;
    for (int q = 0; q < 4; ++q) {
        int j = jbase + wv * 4 + q;
        const float4* wr = (const float4*)(fw2 + (size_t)j * 1024);
        float s = 0.0f;
#pragma unroll
        for (int i2 = 0; i2 < 4; ++i2) {
            float4 a = vv[lane + 64*i2], b = bb1[lane + 64*i2], ww = wr[lane + 64*i2];
            s += (a.x+b.x)*ww.x + (a.y+b.y)*ww.y + (a.z+b.z)*ww.z + (a.w+b.w)*ww.w;
        }
#pragma unroll
        for (int off = 32; off > 0; off >>= 1) s += __shfl_down(s, off, 64);
        if (lane == 0) f2loc[wv * 4 + q] = s + fb2[j];
    }
    __syncthreads();
    for (int kk = 0; kk < 16; ++kk) {
        int k = wv * 16 + kk;
        float v = 0.0f;
        if (lane < 16) v = fw3[(size_t)k * 1024 + jbase + lane] * f2loc[lane];
#pragma unroll
        for (int off = 8; off > 0; off >>= 1) v += __shfl_down(v, off, 16);
        if (lane == 0) {
            if (blockIdx.x == 0) v += fb3[k];
            atomicAdd(&out[k], v);
        }
    }
}

extern "C" void kernel_launch(void* const* d_in, const int* in_sizes, int n_in,
                              void* d_out, int out_size, void* d_ws, size_t ws_size,
                              hipStream_t stream) {
    const float* x   = (const float*)d_in[0];
    const int*   ei  = (const int*)d_in[1];
    const float* W1  = (const float*)d_in[2];
    const float* b1  = (const float*)d_in[3];
    const float* W2  = (const float*)d_in[4];
    const float* b2  = (const float*)d_in[5];
    const float* k1  = (const float*)d_in[6];
    const float* kb1 = (const float*)d_in[7];
    const float* k2  = (const float*)d_in[8];
    const float* kb2 = (const float*)d_in[9];
    const float* k3  = (const float*)d_in[10];
    const float* kb3 = (const float*)d_in[11];
    const float* k4  = (const float*)d_in[12];
    const float* kb4 = (const float*)d_in[13];
    const float* fw1 = (const float*)d_in[14];
    const float* fb1 = (const float*)d_in[15];
    const float* fw2 = (const float*)d_in[16];
    const float* fb2 = (const float*)d_in[17];
    const float* fw3 = (const float*)d_in[18];
    const float* fb3 = (const float*)d_in[19];

    int n = in_sizes[0] / 6;       // 1000
    int E = in_sizes[1] / 2;       // 8000
    const int* row = ei;
    const int* col = ei + E;

    float* ws   = (float*)d_ws;
    float* deg  = ws;              // 1024 (fully written by kA deg scan)
    float* agg1 = ws + 1024;       // 32000 (agg1+agg2 contiguous, zeroed in kA)
    float* agg2 = agg1 + 32000;    // 32000
    float* f1   = agg2 + 32000;    // 1024 (16B aligned, zeroed in kA)

    const int B = 256;
    int st = (E + n) * 32;

    kA_prep<<<n, B, 0, stream>>>(col, deg, agg1, f1, (float*)d_out, n, E);
    kB_scatter1<<<(st + B - 1) / B, B, 0, stream>>>(x, W1, deg, row, col, agg1, E, n);
    kC_scatter2<<<(st + B - 1) / B, B, 0, stream>>>(agg1, b1, W2, deg, row, col, agg2, E, n);
    kD_conv_fc1<<<240, B, 0, stream>>>(agg2, b2, k1, kb1, k2, kb2, k3, kb3, k4, kb4, fw1, f1);
    kF_fc23<<<64, B, 0, stream>>>(f1, fb1, fw2, fb2, fw3, fb3, (float*)d_out);
}